// Round 1
// baseline (1461.700 us; speedup 1.0000x reference)
//
#include <hip/hip_runtime.h>
#include <hip/hip_bf16.h>

#define B_ 128
#define T_ 512
#define C_ 1024

typedef __attribute__((ext_vector_type(8))) short short8;
typedef __attribute__((ext_vector_type(4))) float f32x4;

__device__ __forceinline__ unsigned short f2bf(float f){
  unsigned u; __builtin_memcpy(&u, &f, 4);
  u += 0x7FFFu + ((u >> 16) & 1u);          // RNE
  return (unsigned short)(u >> 16);
}

// ---- async global->LDS 16B helper (linear LDS dest: wave-uniform base + lane*16)
typedef __attribute__((address_space(3))) unsigned lds_u32_t;
typedef __attribute__((address_space(1))) unsigned glb_u32_t;
__device__ __forceinline__ void gload16(const void* g, void* l){
  __builtin_amdgcn_global_load_lds((const glb_u32_t*)g, (lds_u32_t*)l, 16, 0, 0);
}

// ---------------- cast f32 -> bf16 (vectorized) ----------------
__global__ void cast_f32_bf16(const float* __restrict__ in, unsigned short* __restrict__ out, long n){
  long i = (long)blockIdx.x * blockDim.x + threadIdx.x;
  long stride = (long)gridDim.x * blockDim.x;
  for (long j = i * 4; j < n; j += stride * 4){
    float4 v = *(const float4*)(in + j);
    ushort4 o; o.x = f2bf(v.x); o.y = f2bf(v.y); o.z = f2bf(v.z); o.w = f2bf(v.w);
    *(ushort4*)(out + j) = o;
  }
}

// ---------------- transpose-cast W_proj (e,c) -> WpT (c,e) bf16 ----------------
__global__ void transpose_cast(const float* __restrict__ in, unsigned short* __restrict__ out){
  __shared__ float tile[32][33];
  int c0 = blockIdx.x * 32, e0 = blockIdx.y * 32;
  int tx = threadIdx.x, ty = threadIdx.y;     // (32,8)
  for (int r = 0; r < 32; r += 8)
    tile[ty + r][tx] = in[(size_t)(e0 + ty + r) * C_ + c0 + tx];
  __syncthreads();
  for (int r = 0; r < 32; r += 8)
    out[(size_t)(c0 + ty + r) * C_ + e0 + tx] = f2bf(tile[tx][ty + r]);
}

// ---------------- bf16 GEMM, C[m,n] = sum_k A[m,k]*Bt[n,k]  (m97-style 128x128, BK=32) ----------------
__global__ __launch_bounds__(256) void gemm_bt_bf16(
    const unsigned short* __restrict__ A,   // M x K
    const unsigned short* __restrict__ Bt,  // N x K
    unsigned short* __restrict__ Cc,        // M x N (bf16 out)
    int M, int N, int K)
{
  __shared__ short As[128 * 32];
  __shared__ short Bs[128 * 32];
  const int tid  = threadIdx.x;
  const int lane = tid & 63;
  const int wave = tid >> 6;
  const int wr = wave >> 1, wc = wave & 1;
  const int lr = lane & 15, kg = lane >> 4;
  const int m0 = blockIdx.x * 128;
  const int n0 = blockIdx.y * 128;

  f32x4 acc[4][4];
  #pragma unroll
  for (int mi = 0; mi < 4; mi++)
    #pragma unroll
    for (int ni = 0; ni < 4; ni++)
      acc[mi][ni] = (f32x4){0.f, 0.f, 0.f, 0.f};

  const int r1 = tid >> 2, ch1 = tid & 3;       // staging slot: row r1, 16B chunk ch1
  char* abase = (char*)As + (tid & ~63) * 16;   // wave-uniform LDS base
  char* bbase = (char*)Bs + (tid & ~63) * 16;

  for (int k0 = 0; k0 < K; k0 += 32){
    __syncthreads();
    gload16(A  + (size_t)(m0 + r1)      * K + k0 + ch1 * 8, abase);
    gload16(A  + (size_t)(m0 + 64 + r1) * K + k0 + ch1 * 8, abase + 4096);
    gload16(Bt + (size_t)(n0 + r1)      * K + k0 + ch1 * 8, bbase);
    gload16(Bt + (size_t)(n0 + 64 + r1) * K + k0 + ch1 * 8, bbase + 4096);
    __syncthreads();

    short8 af[4], bfr[4];
    #pragma unroll
    for (int mi = 0; mi < 4; mi++)
      af[mi] = *(const short8*)&As[(wr * 64 + mi * 16 + lr) * 32 + kg * 8];
    #pragma unroll
    for (int ni = 0; ni < 4; ni++)
      bfr[ni] = *(const short8*)&Bs[(wc * 64 + ni * 16 + lr) * 32 + kg * 8];
    #pragma unroll
    for (int mi = 0; mi < 4; mi++)
      #pragma unroll
      for (int ni = 0; ni < 4; ni++)
        acc[mi][ni] = __builtin_amdgcn_mfma_f32_16x16x32_bf16(af[mi], bfr[ni], acc[mi][ni], 0, 0, 0);
  }

  // epilogue: D row=(lane>>4)*4+j, col=lane&15  [m89-verified]
  #pragma unroll
  for (int mi = 0; mi < 4; mi++)
    #pragma unroll
    for (int ni = 0; ni < 4; ni++){
      int n = n0 + wc * 64 + ni * 16 + lr;
      int mb = m0 + wr * 64 + mi * 16 + kg * 4;
      #pragma unroll
      for (int j = 0; j < 4; j++)
        Cc[(size_t)(mb + j) * N + n] = f2bf(acc[mi][ni][j]);
    }
}

// ---------------- z table: zt[k][c] = line[k] ^ (2 + 100*sigmoid(pow_[c])), bf16 ----------------
__global__ void zt_kernel(const float* __restrict__ pw, const float* __restrict__ line,
                          unsigned short* __restrict__ zt){
  int k = blockIdx.x;
  float lv = line[k];
  float ll = (lv > 0.f) ? logf(lv) : 0.f;
  #pragma unroll
  for (int q = 0; q < 4; q++){
    int c = threadIdx.x + q * 256;
    float p = pw[c];
    float e = 2.0f + 100.0f / (1.0f + expf(-p));
    float z = (lv > 0.f) ? expf(e * ll) : 0.0f;
    zt[(size_t)k * C_ + c] = f2bf(z);
  }
}

// ---------------- causal conv + gain + relu ----------------
// y[b,t,c] = sum_{s<=t} z[c][t-s] * v[b,s,c];  out = relu(y*gain)
// block: (b, 16-row t-tile, 512-ch slice). 256 thr, 2 ch/thread.
#define CW 512
__global__ __launch_bounds__(256) void conv_kernel(
    const unsigned short* __restrict__ v,    // (B,T,C) bf16
    const unsigned short* __restrict__ zt,   // (T,C) bf16
    const float* __restrict__ gain,          // (C)
    float* __restrict__ out)                 // (B,T,C) f32
{
  __shared__ unsigned short zbuf[31 * CW];
  __shared__ unsigned short vbuf[16 * CW];
  const int b = blockIdx.x;
  const int t0 = blockIdx.y * 16;
  const int cbase = blockIdx.z * CW;
  const int tid = threadIdx.x;
  const int cp = tid * 2;                     // channel pair within slice

  float acc[16][2] = {};

  for (int s0 = 0; s0 <= t0; s0 += 16){
    const int d = t0 - s0;                    // multiple of 16
    // stage z rows k = d-15 .. d+15 (31 rows); k<0 -> zeros (handles triangle)
    #pragma unroll
    for (int j = 0; j < 31; j++){
      int k = d - 15 + j;
      unsigned val = 0;
      if (k >= 0) val = *(const unsigned*)&zt[(size_t)k * C_ + cbase + cp];
      *(unsigned*)&zbuf[j * CW + cp] = val;
    }
    // stage v rows s0..s0+15
    #pragma unroll
    for (int j = 0; j < 16; j++){
      int s = s0 + j;
      *(unsigned*)&vbuf[j * CW + cp] = *(const unsigned*)&v[((size_t)b * T_ + s) * C_ + cbase + cp];
    }
    __syncthreads();

    float zz0[31], zz1[31], vv0[16], vv1[16];
    #pragma unroll
    for (int j = 0; j < 31; j++){
      unsigned u = *(const unsigned*)&zbuf[j * CW + cp];
      zz0[j] = __uint_as_float(u << 16);
      zz1[j] = __uint_as_float(u & 0xffff0000u);
    }
    #pragma unroll
    for (int j = 0; j < 16; j++){
      unsigned u = *(const unsigned*)&vbuf[j * CW + cp];
      vv0[j] = __uint_as_float(u << 16);
      vv1[j] = __uint_as_float(u & 0xffff0000u);
    }
    #pragma unroll
    for (int ss = 0; ss < 16; ss++){
      float a0 = vv0[ss], a1 = vv1[ss];
      #pragma unroll
      for (int tt = 0; tt < 16; tt++){
        int slot = 15 + tt - ss;              // z[k], k = d + tt - ss (0 if k<0)
        acc[tt][0] += zz0[slot] * a0;
        acc[tt][1] += zz1[slot] * a1;
      }
    }
    __syncthreads();
  }

  float g0 = gain[cbase + cp], g1 = gain[cbase + cp + 1];
  #pragma unroll
  for (int tt = 0; tt < 16; tt++){
    float2 o;
    o.x = fmaxf(acc[tt][0] * g0, 0.f);
    o.y = fmaxf(acc[tt][1] * g1, 0.f);
    *(float2*)&out[((size_t)b * T_ + t0 + tt) * C_ + cbase + cp] = o;
  }
}

extern "C" void kernel_launch(void* const* d_in, const int* in_sizes, int n_in,
                              void* d_out, int out_size, void* d_ws, size_t ws_size,
                              hipStream_t stream)
{
  (void)in_sizes; (void)n_in; (void)out_size; (void)ws_size;
  const float* x    = (const float*)d_in[0];
  const float* Wp   = (const float*)d_in[1];
  const float* Wv   = (const float*)d_in[2];
  const float* gain = (const float*)d_in[3];
  const float* pw   = (const float*)d_in[4];
  const float* line = (const float*)d_in[5];
  float* out = (float*)d_out;

  // workspace layout (needs ~142 MB)
  char* ws = (char*)d_ws;
  unsigned short* v_bf  = (unsigned short*)ws;                               // 128 MB
  unsigned short* WpT   = (unsigned short*)(ws + 134217728);                 // 2 MB
  unsigned short* Wv_bf = (unsigned short*)(ws + 134217728 + 2097152);       // 2 MB
  unsigned short* W_f   = (unsigned short*)(ws + 134217728 + 2 * 2097152);   // 2 MB
  unsigned short* zt    = (unsigned short*)(ws + 134217728 + 3 * 2097152);   // 1 MB
  unsigned short* x_bf  = (unsigned short*)d_out;  // scratch in d_out's first 128MB (dead before conv writes)

  // K0: weight preps
  cast_f32_bf16<<<256, 256, 0, stream>>>(Wv, Wv_bf, (long)C_ * C_);
  transpose_cast<<<dim3(32, 32), dim3(32, 8), 0, stream>>>(Wp, WpT);
  // K1: W_f[d,c] = sum_e Wv[d,e] * Wp[e,c]   (A=Wv_bf, Bt=WpT)
  gemm_bt_bf16<<<dim3(8, 8), 256, 0, stream>>>(Wv_bf, WpT, W_f, C_, C_, C_);
  // K2: cast x
  cast_f32_bf16<<<2048, 256, 0, stream>>>(x, x_bf, (long)B_ * T_ * C_);
  // K3: v[m,d] = sum_c x[m,c] * W_f[d,c]
  gemm_bt_bf16<<<dim3(512, 8), 256, 0, stream>>>(x_bf, W_f, v_bf, B_ * T_, C_, C_);
  // K4: decay table
  zt_kernel<<<512, 256, 0, stream>>>(pw, line, zt);
  // K5: causal conv + gain + relu
  conv_kernel<<<dim3(B_, T_ / 16, C_ / CW), 256, 0, stream>>>(v_bf, zt, gain, out);
}

// Round 2
// 540.468 us; speedup vs baseline: 2.7045x; 2.7045x over previous
//
#include <hip/hip_runtime.h>
#include <hip/hip_bf16.h>

#define B_ 128
#define T_ 512
#define C_ 1024

typedef __attribute__((ext_vector_type(8))) short short8;
typedef __attribute__((ext_vector_type(4))) float f32x4;

__device__ __forceinline__ unsigned short f2bf(float f){
  unsigned u; __builtin_memcpy(&u, &f, 4);
  u += 0x7FFFu + ((u >> 16) & 1u);          // RNE
  return (unsigned short)(u >> 16);
}

// ---- async global->LDS 16B (LDS dest: wave-uniform base + lane*16)
typedef __attribute__((address_space(3))) unsigned lds_u32_t;
typedef __attribute__((address_space(1))) unsigned glb_u32_t;
__device__ __forceinline__ void gload16(const void* g, void* l){
  __builtin_amdgcn_global_load_lds((const glb_u32_t*)g, (lds_u32_t*)l, 16, 0, 0);
}

// ---------------- cast f32 -> bf16 (vectorized) ----------------
__global__ void cast_f32_bf16(const float* __restrict__ in, unsigned short* __restrict__ out, long n){
  long i = (long)blockIdx.x * blockDim.x + threadIdx.x;
  long stride = (long)gridDim.x * blockDim.x;
  for (long j = i * 4; j < n; j += stride * 4){
    float4 v = *(const float4*)(in + j);
    ushort4 o; o.x = f2bf(v.x); o.y = f2bf(v.y); o.z = f2bf(v.z); o.w = f2bf(v.w);
    *(ushort4*)(out + j) = o;
  }
}

// ---------------- transpose-cast W_proj (e,c) -> WpT (c,e) bf16 ----------------
__global__ void transpose_cast(const float* __restrict__ in, unsigned short* __restrict__ out){
  __shared__ float tile[32][33];
  int c0 = blockIdx.x * 32, e0 = blockIdx.y * 32;
  int tx = threadIdx.x, ty = threadIdx.y;     // (32,8)
  for (int r = 0; r < 32; r += 8)
    tile[ty + r][tx] = in[(size_t)(e0 + ty + r) * C_ + c0 + tx];
  __syncthreads();
  for (int r = 0; r < 32; r += 8)
    out[(size_t)(c0 + ty + r) * C_ + e0 + tx] = f2bf(tile[tx][ty + r]);
}

// ---------------- bf16 GEMM, C[m,n] = sum_k A[m,k]*Bt[n,k]  (row-major bf16 out) ----------------
__global__ __launch_bounds__(256) void gemm_bt_bf16(
    const unsigned short* __restrict__ A,   // M x K
    const unsigned short* __restrict__ Bt,  // N x K
    unsigned short* __restrict__ Cc,        // M x N
    int M, int N, int K)
{
  __shared__ short As[128 * 32];
  __shared__ short Bs[128 * 32];
  const int tid  = threadIdx.x;
  const int lane = tid & 63;
  const int wave = tid >> 6;
  const int wr = wave >> 1, wc = wave & 1;
  const int lr = lane & 15, kg = lane >> 4;
  const int m0 = blockIdx.x * 128;
  const int n0 = blockIdx.y * 128;

  f32x4 acc[4][4];
  #pragma unroll
  for (int mi = 0; mi < 4; mi++)
    #pragma unroll
    for (int ni = 0; ni < 4; ni++)
      acc[mi][ni] = (f32x4){0.f, 0.f, 0.f, 0.f};

  const int r1 = tid >> 2, ch1 = tid & 3;
  char* abase = (char*)As + (tid & ~63) * 16;
  char* bbase = (char*)Bs + (tid & ~63) * 16;

  for (int k0 = 0; k0 < K; k0 += 32){
    __syncthreads();
    gload16(A  + (size_t)(m0 + r1)      * K + k0 + ch1 * 8, abase);
    gload16(A  + (size_t)(m0 + 64 + r1) * K + k0 + ch1 * 8, abase + 4096);
    gload16(Bt + (size_t)(n0 + r1)      * K + k0 + ch1 * 8, bbase);
    gload16(Bt + (size_t)(n0 + 64 + r1) * K + k0 + ch1 * 8, bbase + 4096);
    __syncthreads();

    short8 af[4], bfr[4];
    #pragma unroll
    for (int mi = 0; mi < 4; mi++)
      af[mi] = *(const short8*)&As[(wr * 64 + mi * 16 + lr) * 32 + kg * 8];
    #pragma unroll
    for (int ni = 0; ni < 4; ni++)
      bfr[ni] = *(const short8*)&Bs[(wc * 64 + ni * 16 + lr) * 32 + kg * 8];
    #pragma unroll
    for (int mi = 0; mi < 4; mi++)
      #pragma unroll
      for (int ni = 0; ni < 4; ni++)
        acc[mi][ni] = __builtin_amdgcn_mfma_f32_16x16x32_bf16(af[mi], bfr[ni], acc[mi][ni], 0, 0, 0);
  }

  #pragma unroll
  for (int mi = 0; mi < 4; mi++)
    #pragma unroll
    for (int ni = 0; ni < 4; ni++){
      int n = n0 + wc * 64 + ni * 16 + lr;
      int mb = m0 + wr * 64 + mi * 16 + kg * 4;
      #pragma unroll
      for (int j = 0; j < 4; j++)
        Cc[(size_t)(mb + j) * N + n] = f2bf(acc[mi][ni][j]);
    }
}

// ---------------- same GEMM, epilogue writes vt (C,B,T):  vt[n][m>>9][m&511] ----------------
__global__ __launch_bounds__(256) void gemm_bt_vt(
    const unsigned short* __restrict__ A,   // M x K   (M = B*T, row m = b*T + t)
    const unsigned short* __restrict__ Bt,  // N x K   (N = C)
    unsigned short* __restrict__ vt,        // (C, B, T)
    int M, int N, int K)
{
  __shared__ short As[128 * 32];
  __shared__ short Bs[128 * 32];
  const int tid  = threadIdx.x;
  const int lane = tid & 63;
  const int wave = tid >> 6;
  const int wr = wave >> 1, wc = wave & 1;
  const int lr = lane & 15, kg = lane >> 4;
  const int m0 = blockIdx.x * 128;
  const int n0 = blockIdx.y * 128;

  f32x4 acc[4][4];
  #pragma unroll
  for (int mi = 0; mi < 4; mi++)
    #pragma unroll
    for (int ni = 0; ni < 4; ni++)
      acc[mi][ni] = (f32x4){0.f, 0.f, 0.f, 0.f};

  const int r1 = tid >> 2, ch1 = tid & 3;
  char* abase = (char*)As + (tid & ~63) * 16;
  char* bbase = (char*)Bs + (tid & ~63) * 16;

  for (int k0 = 0; k0 < K; k0 += 32){
    __syncthreads();
    gload16(A  + (size_t)(m0 + r1)      * K + k0 + ch1 * 8, abase);
    gload16(A  + (size_t)(m0 + 64 + r1) * K + k0 + ch1 * 8, abase + 4096);
    gload16(Bt + (size_t)(n0 + r1)      * K + k0 + ch1 * 8, bbase);
    gload16(Bt + (size_t)(n0 + 64 + r1) * K + k0 + ch1 * 8, bbase + 4096);
    __syncthreads();

    short8 af[4], bfr[4];
    #pragma unroll
    for (int mi = 0; mi < 4; mi++)
      af[mi] = *(const short8*)&As[(wr * 64 + mi * 16 + lr) * 32 + kg * 8];
    #pragma unroll
    for (int ni = 0; ni < 4; ni++)
      bfr[ni] = *(const short8*)&Bs[(wc * 64 + ni * 16 + lr) * 32 + kg * 8];
    #pragma unroll
    for (int mi = 0; mi < 4; mi++)
      #pragma unroll
      for (int ni = 0; ni < 4; ni++)
        acc[mi][ni] = __builtin_amdgcn_mfma_f32_16x16x32_bf16(af[mi], bfr[ni], acc[mi][ni], 0, 0, 0);
  }

  #pragma unroll
  for (int mi = 0; mi < 4; mi++)
    #pragma unroll
    for (int ni = 0; ni < 4; ni++){
      int n  = n0 + wc * 64 + ni * 16 + lr;        // channel c
      int mb = m0 + wr * 64 + mi * 16 + kg * 4;    // m = b*512 + t (4 consecutive t)
      int b  = mb >> 9, t = mb & 511;
      ushort4 o;
      o.x = f2bf(acc[mi][ni][0]); o.y = f2bf(acc[mi][ni][1]);
      o.z = f2bf(acc[mi][ni][2]); o.w = f2bf(acc[mi][ni][3]);
      *(ushort4*)&vt[((size_t)n * B_ + b) * T_ + t] = o;
    }
}

// ---------------- Toeplitz band table: band[c][d32][i][j] = z_c[32*d32 + i - j] ----------------
// rows padded to 40 shorts (80B) => 16B-aligned, ~conflict-free ds_read_b128
__global__ void band_prep(const float* __restrict__ pw, const float* __restrict__ line,
                          unsigned short* __restrict__ band){
  const int c = blockIdx.x, d32 = blockIdx.y;
  const float p = pw[c];
  const float e = 2.0f + 100.0f / (1.0f + expf(-p));
  const int tid = threadIdx.x;
  for (int idx = tid; idx < 1280; idx += 256){
    int i = idx / 40, j = idx - i * 40;
    int k = d32 * 32 + i - j;
    float z = 0.f;
    if (j < 32 && k >= 0 && k < T_){
      float lv = line[k];
      z = (lv > 0.f) ? expf(e * logf(lv)) : 0.f;
    }
    band[((size_t)c * 16 + d32) * 1280 + idx] = f2bf(z);
  }
}

// ---------------- conv via MFMA: per (c, t-tile 128) block, Y[t][b] = sum_s z[t-s] v[b][s] ----
__global__ __launch_bounds__(256) void conv_mfma(
    const unsigned short* __restrict__ vt,    // (C, B, T) bf16
    const unsigned short* __restrict__ band,  // (C, 16, 32, 40) bf16
    const float* __restrict__ gain,           // (1,1,C)
    unsigned short* __restrict__ Ybf)         // (C, B, T) bf16, gain+relu applied
{
  __shared__ short Bs[128 * 32];      // v tile: 128 b x 32 s
  __shared__ short Ab[16 * 1280];     // up to 16 Toeplitz bands (40KB)
  const int c  = blockIdx.x;
  const int t0 = blockIdx.y << 7;
  const int tid = threadIdx.x, lane = tid & 63, wave = tid >> 6;
  const int wr = wave >> 1, wc = wave & 1, lr = lane & 15, kg = lane >> 4;
  const int K  = t0 + 128;            // causal: s < t0+128
  const int nb = (t0 >> 5) + 4;       // bands d32 = 0..nb-1

  // stage all needed bands once (linear gload16)
  {
    const unsigned short* src = band + (size_t)c * (16 * 1280);
    const int nch = nb * 160;                      // 16B chunks
    for (int q0 = 0; q0 < nch; q0 += 256){
      int q = q0 + tid;
      char* dst = (char*)Ab + q0 * 16 + wave * 1024;   // wave-uniform
      if (q < nch) gload16(src + (size_t)q * 8, dst);
    }
  }

  f32x4 acc[4][4];
  #pragma unroll
  for (int mi = 0; mi < 4; mi++)
    #pragma unroll
    for (int ni = 0; ni < 4; ni++)
      acc[mi][ni] = (f32x4){0.f, 0.f, 0.f, 0.f};

  const int r1 = tid >> 2, ch1 = tid & 3;
  char* bbase = (char*)Bs + (tid & ~63) * 16;
  const size_t vbase = (size_t)c * B_ * T_;

  for (int k0 = 0; k0 < K; k0 += 32){
    __syncthreads();
    gload16(vt + vbase + (size_t)r1 * T_        + k0 + ch1 * 8, bbase);
    gload16(vt + vbase + (size_t)(64 + r1) * T_ + k0 + ch1 * 8, bbase + 4096);
    __syncthreads();

    short8 bfr[4];
    #pragma unroll
    for (int ni = 0; ni < 4; ni++)
      bfr[ni] = *(const short8*)&Bs[(wc * 64 + ni * 16 + lr) * 32 + kg * 8];

    const int dbase = ((t0 - k0) >> 5) + wr * 2;
    #pragma unroll
    for (int mi = 0; mi < 4; mi++){
      const int d32 = dbase + (mi >> 1);         // wave-uniform per mi
      if (d32 >= 0){
        const int i = ((mi & 1) << 4) + lr;      // row within band
        short8 af = *(const short8*)&Ab[d32 * 1280 + i * 40 + kg * 8];
        #pragma unroll
        for (int ni = 0; ni < 4; ni++)
          acc[mi][ni] = __builtin_amdgcn_mfma_f32_16x16x32_bf16(af, bfr[ni], acc[mi][ni], 0, 0, 0);
      }
    }
  }

  const float g = gain[c];
  #pragma unroll
  for (int mi = 0; mi < 4; mi++)
    #pragma unroll
    for (int ni = 0; ni < 4; ni++){
      int t = t0 + wr * 64 + mi * 16 + kg * 4;   // 4 consecutive t (j)
      int b = wc * 64 + ni * 16 + lr;
      ushort4 o;
      o.x = f2bf(fmaxf(acc[mi][ni][0] * g, 0.f));
      o.y = f2bf(fmaxf(acc[mi][ni][1] * g, 0.f));
      o.z = f2bf(fmaxf(acc[mi][ni][2] * g, 0.f));
      o.w = f2bf(fmaxf(acc[mi][ni][3] * g, 0.f));
      *(ushort4*)&Ybf[((size_t)c * B_ + b) * T_ + t] = o;
    }
}

// ---------------- final: (C,B,T) bf16 -> (B,T,C) f32 ----------------
__global__ __launch_bounds__(256) void final_out(const unsigned short* __restrict__ Ybf,
                                                 float* __restrict__ out){
  __shared__ unsigned short tile[64][72];
  const int c0 = blockIdx.x * 64;
  const int t0 = blockIdx.y * 64;
  const int b  = blockIdx.z;
  const int tid = threadIdx.x;
  const int cr = tid >> 4;
  const int t4 = (tid & 15) * 4;
  for (int q = 0; q < 64; q += 16){
    ushort4 u = *(const ushort4*)&Ybf[((size_t)(c0 + cr + q) * B_ + b) * T_ + t0 + t4];
    *(ushort4*)&tile[cr + q][t4] = u;
  }
  __syncthreads();
  const int tr = tid >> 4;
  const int c4 = (tid & 15) * 4;
  for (int q = 0; q < 64; q += 16){
    int t = tr + q;
    float4 o;
    o.x = __uint_as_float((unsigned)tile[c4 + 0][t] << 16);
    o.y = __uint_as_float((unsigned)tile[c4 + 1][t] << 16);
    o.z = __uint_as_float((unsigned)tile[c4 + 2][t] << 16);
    o.w = __uint_as_float((unsigned)tile[c4 + 3][t] << 16);
    *(float4*)&out[((size_t)b * T_ + t0 + t) * C_ + c0 + c4] = o;
  }
}

extern "C" void kernel_launch(void* const* d_in, const int* in_sizes, int n_in,
                              void* d_out, int out_size, void* d_ws, size_t ws_size,
                              hipStream_t stream)
{
  (void)in_sizes; (void)n_in; (void)out_size; (void)ws_size;
  const float* x    = (const float*)d_in[0];
  const float* Wp   = (const float*)d_in[1];
  const float* Wv   = (const float*)d_in[2];
  const float* gain = (const float*)d_in[3];
  const float* pw   = (const float*)d_in[4];
  const float* line = (const float*)d_in[5];
  float* out = (float*)d_out;

  // ws: [Ybf 128MB][WpT 2MB][Wv_bf 2MB][W_f 2MB]  (~134MB)
  char* ws = (char*)d_ws;
  unsigned short* Ybf   = (unsigned short*)ws;
  unsigned short* WpT   = (unsigned short*)(ws + 134217728);
  unsigned short* Wv_bf = (unsigned short*)(ws + 134217728 + 2097152);
  unsigned short* W_f   = (unsigned short*)(ws + 134217728 + 2 * 2097152);
  // d_out (256MB f32) reused as scratch with ping-pong lifetimes:
  unsigned short* x_bf = (unsigned short*)d_out;                    // lower 128MB (dead after GEMM)
  unsigned short* vt   = (unsigned short*)d_out + 67108864;         // upper 128MB (dead after conv)
  unsigned short* bandp = (unsigned short*)d_out;                   // lower 40MB, written AFTER GEMM

  // weights
  cast_f32_bf16<<<256, 256, 0, stream>>>(Wv, Wv_bf, (long)C_ * C_);
  transpose_cast<<<dim3(32, 32), dim3(32, 8), 0, stream>>>(Wp, WpT);
  gemm_bt_bf16<<<dim3(8, 8), 256, 0, stream>>>(Wv_bf, WpT, W_f, C_, C_, C_);
  // x -> bf16
  cast_f32_bf16<<<2048, 256, 0, stream>>>(x, x_bf, (long)B_ * T_ * C_);
  // v = x @ W_f^T, written directly as (C,B,T)
  gemm_bt_vt<<<dim3(512, 8), 256, 0, stream>>>(x_bf, W_f, vt, B_ * T_, C_, C_);
  // Toeplitz bands (overwrites x_bf region — dead now)
  band_prep<<<dim3(1024, 16), 256, 0, stream>>>(pw, line, bandp);
  // conv + gain + relu -> Ybf (C,B,T)
  conv_mfma<<<dim3(C_, T_ / 128), 256, 0, stream>>>(vt, bandp, gain, Ybf);
  // transpose to (B,T,C) f32
  final_out<<<dim3(16, 8, 128), 256, 0, stream>>>(Ybf, out);
}